// Round 8
// baseline (148.040 us; speedup 1.0000x reference)
//
#include <hip/hip_runtime.h>

#define N_NODES 10000
#define N_EDGES 320000
#define F 256          // F_IN == F_OUT
#define K2 512         // 2*F_IN
#define SLOTS 160      // per-node edge bucket capacity (max deg ~Poisson(32) << 160)
#define N_TILE64 157   // ceil(10000/64)
#define FEAT_BLOCKS 2500  // N*F/4/256
#define W_BLOCKS 128      // F*K2/4/256
#define LDSROW 264        // 256 + 8 bf16 pad -> 528B row stride (2-way banks = free)

typedef __attribute__((ext_vector_type(8))) __bf16 bf16x8;
typedef __attribute__((ext_vector_type(4))) __bf16 bf16x4;
typedef __attribute__((ext_vector_type(4))) float f32x4;
typedef unsigned long long u64;
typedef unsigned int u32;
typedef unsigned short u16;

__device__ inline float bf2f(u16 u) { u32 x = ((u32)u) << 16; return __uint_as_float(x); }

// Wt layout: Wt[t][kq][col][8e], t=k/32, kq=(k%32)/8, e=k%8 (fragment-contiguous).

// ---------- prep: featb (plain bf16 rows) + Wt (h0 folded) + cnt = 0
__global__ __launch_bounds__(256) void prep_kernel(
    const float* __restrict__ feat,
    const float* __restrict__ Wm,
    const int* __restrict__ src,
    __bf16* __restrict__ featb,
    __bf16* __restrict__ Wt,
    int* __restrict__ cnt) {
  int b = blockIdx.x;
  int tid = threadIdx.x;
  if (b < FEAT_BLOCKS) {
    int idx = b * 256 + tid;                 // float4 index over feat
    float4 v = ((const float4*)feat)[idx];
    bf16x4 o;
    o[0] = (__bf16)v.x; o[1] = (__bf16)v.y; o[2] = (__bf16)v.z; o[3] = (__bf16)v.w;
    *(bf16x4*)(featb + (size_t)idx * 4) = o;
    if (idx < N_NODES) cnt[idx] = 0;
  } else {
    int idx = (b - FEAT_BLOCKS) * 256 + tid; // float4 index over W
    int o_ = idx >> 7;                       // 128 float4 per W row
    int k = (idx & 127) * 4;
    float4 w = ((const float4*)Wm)[idx];
    if (k >= F) {
      int s0 = src[0];
      float4 h = ((const float4*)(feat + (size_t)s0 * F))[(k - F) >> 2];
      w.x *= h.x; w.y *= h.y; w.z *= h.z; w.w *= h.w;
    }
    bf16x4 o;
    o[0] = (__bf16)w.x; o[1] = (__bf16)w.y; o[2] = (__bf16)w.z; o[3] = (__bf16)w.w;
    int t = k >> 5, kq = (k & 31) >> 3, e = k & 7;
    size_t offT = (((size_t)t * 4 + kq) * 256 + o_) * 8 + e;
    *(bf16x4*)(Wt + offT) = o;
  }
}

// ---------- bucket scatter: bucket[d][slot] = (ew,src); cnt[d] = degree
__global__ __launch_bounds__(256) void scatter_kernel(
    const int* __restrict__ src,
    const int* __restrict__ dst,
    const float* __restrict__ ew,
    int* __restrict__ cnt,
    u64* __restrict__ bucket) {
  int i = blockIdx.x * 256 + threadIdx.x;
  if (i >= N_EDGES / 4) return;
  int4 s4 = ((const int4*)src)[i];
  int4 d4 = ((const int4*)dst)[i];
  float4 w4 = ((const float4*)ew)[i];
  int p;
  p = atomicAdd(&cnt[d4.x], 1);
  if (p < SLOTS) bucket[(size_t)d4.x * SLOTS + p] = ((u64)__float_as_uint(w4.x) << 32) | (u32)s4.x;
  p = atomicAdd(&cnt[d4.y], 1);
  if (p < SLOTS) bucket[(size_t)d4.y * SLOTS + p] = ((u64)__float_as_uint(w4.y) << 32) | (u32)s4.y;
  p = atomicAdd(&cnt[d4.z], 1);
  if (p < SLOTS) bucket[(size_t)d4.z * SLOTS + p] = ((u64)__float_as_uint(w4.z) << 32) | (u32)s4.z;
  p = atomicAdd(&cnt[d4.w], 1);
  if (p < SLOTS) bucket[(size_t)d4.w * SLOTS + p] = ((u64)__float_as_uint(w4.w) << 32) | (u32)s4.w;
}

// ---------- fused: per-block aggregate 64 nodes into LDS, then 64x256 MFMA tile
__global__ __launch_bounds__(256) void fused_agg_gemm_kernel(
    const __bf16* __restrict__ featb,   // [N][F] plain
    const u64* __restrict__ bucket,     // [N][SLOTS]
    const int* __restrict__ cnt,        // [N]
    const __bf16* __restrict__ Wt,      // [16][4][256][8]
    const float* __restrict__ bias,
    float* __restrict__ out) {          // [N][F]
  __shared__ __bf16 aggs[64][LDSROW];   // 64 rows x 528B stride = 33.8KB

  const int tid = threadIdx.x;
  const int wave = tid >> 6;
  const int lane = tid & 63;
  const int m0 = blockIdx.x * 64;

  // ---- agg phase: wave aggregates nodes m0 + wave*16 + j, j=0..15
  for (int j = 0; j < 16; ++j) {
    int node = m0 + wave * 16 + j;
    float ax = 0.f, ay = 0.f, az = 0.f, aw = 0.f;
    float ic = 0.f;
    if (node < N_NODES) {
      int c = cnt[node];
      ic = 1.0f / (float)max(c, 1);
      int cc = min(c, SLOTS);
      const u64* bk = bucket + (size_t)node * SLOTS;
      const ushort4* f4 = (const ushort4*)featb;
      int i = 0;
      for (; i + 4 <= cc; i += 4) {
        u64 p0 = bk[i], p1 = bk[i + 1], p2 = bk[i + 2], p3 = bk[i + 3];
        ushort4 v0 = f4[(size_t)(u32)p0 * 64 + lane];
        ushort4 v1 = f4[(size_t)(u32)p1 * 64 + lane];
        ushort4 v2 = f4[(size_t)(u32)p2 * 64 + lane];
        ushort4 v3 = f4[(size_t)(u32)p3 * 64 + lane];
        float w0 = __uint_as_float((u32)(p0 >> 32));
        float w1 = __uint_as_float((u32)(p1 >> 32));
        float w2 = __uint_as_float((u32)(p2 >> 32));
        float w3 = __uint_as_float((u32)(p3 >> 32));
        ax += bf2f(v0.x) * w0 + bf2f(v1.x) * w1 + bf2f(v2.x) * w2 + bf2f(v3.x) * w3;
        ay += bf2f(v0.y) * w0 + bf2f(v1.y) * w1 + bf2f(v2.y) * w2 + bf2f(v3.y) * w3;
        az += bf2f(v0.z) * w0 + bf2f(v1.z) * w1 + bf2f(v2.z) * w2 + bf2f(v3.z) * w3;
        aw += bf2f(v0.w) * w0 + bf2f(v1.w) * w1 + bf2f(v2.w) * w2 + bf2f(v3.w) * w3;
      }
      for (; i < cc; ++i) {
        u64 p0 = bk[i];
        ushort4 v0 = f4[(size_t)(u32)p0 * 64 + lane];
        float w0 = __uint_as_float((u32)(p0 >> 32));
        ax += bf2f(v0.x) * w0; ay += bf2f(v0.y) * w0;
        az += bf2f(v0.z) * w0; aw += bf2f(v0.w) * w0;
      }
    }
    bf16x4 o;
    o[0] = (__bf16)(ax * ic); o[1] = (__bf16)(ay * ic);
    o[2] = (__bf16)(az * ic); o[3] = (__bf16)(aw * ic);
    *(bf16x4*)(&aggs[wave * 16 + j][lane * 4]) = o;
  }
  __syncthreads();

  // ---- gemm phase: 64 rows x 256 cols; wave = all 64 rows x 64 cols
  const int r15 = lane & 15;
  const int kq = lane >> 4;
  const int col0 = wave * 64;

  f32x4 acc[4][4];
#pragma unroll
  for (int rs = 0; rs < 4; ++rs)
#pragma unroll
    for (int cs = 0; cs < 4; ++cs) acc[rs][cs] = (f32x4){0.f, 0.f, 0.f, 0.f};

#pragma unroll
  for (int t = 0; t < 16; ++t) {
    bf16x8 a[4];
    if (t < 8) {
#pragma unroll
      for (int rs = 0; rs < 4; ++rs) {
        int an = m0 + rs * 16 + r15;
        an = min(an, N_NODES - 1);          // clamp (dead rows never stored)
        a[rs] = *(const bf16x8*)(featb + (size_t)an * F + t * 32 + kq * 8);
      }
    } else {
#pragma unroll
      for (int rs = 0; rs < 4; ++rs)
        a[rs] = *(const bf16x8*)(&aggs[rs * 16 + r15][(t - 8) * 32 + kq * 8]);
    }
#pragma unroll
    for (int cs = 0; cs < 4; ++cs) {
      bf16x8 bb = *(const bf16x8*)(Wt + (((size_t)t * 4 + kq) * 256 + col0 + cs * 16 + r15) * 8);
#pragma unroll
      for (int rs = 0; rs < 4; ++rs)
        acc[rs][cs] = __builtin_amdgcn_mfma_f32_16x16x32_bf16(a[rs], bb, acc[rs][cs], 0, 0, 0);
    }
  }

  // C/D layout: col = lane&15, row = (lane>>4)*4 + reg   [m89-verified]
  const int rbase = kq * 4;
#pragma unroll
  for (int cs = 0; cs < 4; ++cs) {
    int col = col0 + cs * 16 + r15;
    float bv = bias[col];
#pragma unroll
    for (int rs = 0; rs < 4; ++rs) {
#pragma unroll
      for (int r = 0; r < 4; ++r) {
        int orow = m0 + rs * 16 + rbase + r;
        if (orow < N_NODES)
          out[(size_t)orow * F + col] = fmaxf(acc[rs][cs][r] + bv, 0.0f);
      }
    }
  }
}

extern "C" void kernel_launch(void* const* d_in, const int* in_sizes, int n_in,
                              void* d_out, int out_size, void* d_ws, size_t ws_size,
                              hipStream_t stream) {
  const float* feat = (const float*)d_in[0];
  const float* ew   = (const float*)d_in[1];
  const int*   src  = (const int*)d_in[2];
  const int*   dst  = (const int*)d_in[3];
  const float* Wm   = (const float*)d_in[4];
  const float* bias = (const float*)d_in[5];
  float* out = (float*)d_out;

  // workspace layout (8B-aligned first)
  u64*    bucket = (u64*)d_ws;                                  // N*SLOTS  (12.8 MB)
  __bf16* featb  = (__bf16*)(bucket + (size_t)N_NODES * SLOTS); // N*F      (5.12 MB)
  __bf16* Wt     = featb + (size_t)N_NODES * F;                 // F*K2     (0.26 MB)
  int*    cnt    = (int*)(Wt + (size_t)F * K2);                 // N

  prep_kernel<<<FEAT_BLOCKS + W_BLOCKS, 256, 0, stream>>>(feat, Wm, src, featb, Wt, cnt);
  scatter_kernel<<<(N_EDGES / 4 + 255) / 256, 256, 0, stream>>>(src, dst, ew, cnt, bucket);
  fused_agg_gemm_kernel<<<N_TILE64, 256, 0, stream>>>(featb, bucket, cnt, Wt, bias, out);
}

// Round 9
// 86.895 us; speedup vs baseline: 1.7037x; 1.7037x over previous
//
#include <hip/hip_runtime.h>

#define N_NODES 10000
#define N_EDGES 320000
#define F 256          // F_IN == F_OUT
#define K2 512         // 2*F_IN
#define SLOTS 160      // per-node bucket capacity (deg ~Poisson(32), 160 > 20 sigma)
#define N_TILE64 157   // ceil(10000/64)
#define FEAT_BLOCKS 2500  // N*F/4/256
#define W_BLOCKS 128      // F*K2/4/256

typedef __attribute__((ext_vector_type(8))) __bf16 bf16x8;
typedef __attribute__((ext_vector_type(4))) __bf16 bf16x4;
typedef __attribute__((ext_vector_type(4))) float f32x4;
typedef unsigned long long u64;
typedef unsigned int u32;
typedef unsigned short u16;

__device__ inline float bf2f(u16 u) { u32 x = ((u32)u) << 16; return __uint_as_float(x); }

// Wt layout: Wt[t][kq][col][8e], t=k/32, kq=(k%32)/8, e=k%8 (fragment-contiguous).

// ---------- prep: featb (plain bf16 rows) + Wt (h0 folded) + cnt = 0
__global__ __launch_bounds__(256) void prep_kernel(
    const float* __restrict__ feat,
    const float* __restrict__ Wm,
    const int* __restrict__ src,
    __bf16* __restrict__ featb,
    __bf16* __restrict__ Wt,
    int* __restrict__ cnt) {
  int b = blockIdx.x;
  int tid = threadIdx.x;
  if (b < FEAT_BLOCKS) {
    int idx = b * 256 + tid;                 // float4 index over feat
    float4 v = ((const float4*)feat)[idx];
    bf16x4 o;
    o[0] = (__bf16)v.x; o[1] = (__bf16)v.y; o[2] = (__bf16)v.z; o[3] = (__bf16)v.w;
    *(bf16x4*)(featb + (size_t)idx * 4) = o;
    if (idx < N_NODES) cnt[idx] = 0;
  } else {
    int idx = (b - FEAT_BLOCKS) * 256 + tid; // float4 index over W
    int o_ = idx >> 7;                       // 128 float4 per W row
    int k = (idx & 127) * 4;
    float4 w = ((const float4*)Wm)[idx];
    if (k >= F) {
      int s0 = src[0];
      float4 h = ((const float4*)(feat + (size_t)s0 * F))[(k - F) >> 2];
      w.x *= h.x; w.y *= h.y; w.z *= h.z; w.w *= h.w;
    }
    bf16x4 o;
    o[0] = (__bf16)w.x; o[1] = (__bf16)w.y; o[2] = (__bf16)w.z; o[3] = (__bf16)w.w;
    int t = k >> 5, kq = (k & 31) >> 3, e = k & 7;
    size_t offT = (((size_t)t * 4 + kq) * 256 + o_) * 8 + e;
    *(bf16x4*)(Wt + offT) = o;
  }
}

// ---------- bucket scatter: bucket[d][slot] = (ew,src); cnt[d] = degree
__global__ __launch_bounds__(256) void scatter_kernel(
    const int* __restrict__ src,
    const int* __restrict__ dst,
    const float* __restrict__ ew,
    int* __restrict__ cnt,
    u64* __restrict__ bucket) {
  int i = blockIdx.x * 256 + threadIdx.x;
  if (i >= N_EDGES / 4) return;
  int4 s4 = ((const int4*)src)[i];
  int4 d4 = ((const int4*)dst)[i];
  float4 w4 = ((const float4*)ew)[i];
  int p;
  p = atomicAdd(&cnt[d4.x], 1);
  if (p < SLOTS) bucket[(size_t)d4.x * SLOTS + p] = ((u64)__float_as_uint(w4.x) << 32) | (u32)s4.x;
  p = atomicAdd(&cnt[d4.y], 1);
  if (p < SLOTS) bucket[(size_t)d4.y * SLOTS + p] = ((u64)__float_as_uint(w4.y) << 32) | (u32)s4.y;
  p = atomicAdd(&cnt[d4.z], 1);
  if (p < SLOTS) bucket[(size_t)d4.z * SLOTS + p] = ((u64)__float_as_uint(w4.z) << 32) | (u32)s4.z;
  p = atomicAdd(&cnt[d4.w], 1);
  if (p < SLOTS) bucket[(size_t)d4.w * SLOTS + p] = ((u64)__float_as_uint(w4.w) << 32) | (u32)s4.w;
}

// ---------- aggregation: one wave per node (10000 waves), 8-deep pipeline
__global__ __launch_bounds__(256) void node_agg_kernel(
    const __bf16* __restrict__ featb,
    const u64* __restrict__ bucket,
    const int* __restrict__ cnt,
    __bf16* __restrict__ aggb) {
  int node = (blockIdx.x * 256 + threadIdx.x) >> 6;
  int lane = threadIdx.x & 63;
  if (node >= N_NODES) return;
  int c = cnt[node];
  int cc = min(c, SLOTS);
  const u64* bk = bucket + (size_t)node * SLOTS;
  const ushort4* f4 = (const ushort4*)featb;
  float ax = 0.f, ay = 0.f, az = 0.f, aw = 0.f;
  int i = 0;
  for (; i + 8 <= cc; i += 8) {
    u64 p[8];
    ushort4 v[8];
#pragma unroll
    for (int j = 0; j < 8; ++j) p[j] = bk[i + j];
#pragma unroll
    for (int j = 0; j < 8; ++j) v[j] = f4[(size_t)(u32)p[j] * 64 + lane];
#pragma unroll
    for (int j = 0; j < 8; ++j) {
      float w = __uint_as_float((u32)(p[j] >> 32));
      ax += bf2f(v[j].x) * w; ay += bf2f(v[j].y) * w;
      az += bf2f(v[j].z) * w; aw += bf2f(v[j].w) * w;
    }
  }
  for (; i < cc; ++i) {
    u64 p0 = bk[i];
    ushort4 v0 = f4[(size_t)(u32)p0 * 64 + lane];
    float w0 = __uint_as_float((u32)(p0 >> 32));
    ax += bf2f(v0.x) * w0; ay += bf2f(v0.y) * w0;
    az += bf2f(v0.z) * w0; aw += bf2f(v0.w) * w0;
  }
  float ic = 1.0f / (float)max(c, 1);
  bf16x4 o;
  o[0] = (__bf16)(ax * ic); o[1] = (__bf16)(ay * ic);
  o[2] = (__bf16)(az * ic); o[3] = (__bf16)(aw * ic);
  *(bf16x4*)(aggb + (size_t)node * F + lane * 4) = o;
}

// ---------- MFMA GEMM: 64-row x 256-col macro-tile; B reused across 4 row-subtiles
__global__ __launch_bounds__(256) void mfma_gemm_kernel(
    const __bf16* __restrict__ featb,   // [N][F] plain
    const __bf16* __restrict__ aggb,    // [N][F] plain
    const __bf16* __restrict__ Wt,      // [16][4][256][8]
    const float* __restrict__ bias,
    float* __restrict__ out) {          // [N][F]
  const int tid = threadIdx.x;
  const int wave = tid >> 6;
  const int lane = tid & 63;
  const int r15 = lane & 15;
  const int kq = lane >> 4;
  const int col0 = wave * 64;
  const int m0 = blockIdx.x * 64;

  f32x4 acc[4][4];
#pragma unroll
  for (int rs = 0; rs < 4; ++rs)
#pragma unroll
    for (int cs = 0; cs < 4; ++cs) acc[rs][cs] = (f32x4){0.f, 0.f, 0.f, 0.f};

#pragma unroll
  for (int t = 0; t < 16; ++t) {
    bf16x8 a[4];
#pragma unroll
    for (int rs = 0; rs < 4; ++rs) {
      int an = min(m0 + rs * 16 + r15, N_NODES - 1);   // clamp; dead rows never stored
      const __bf16* base = (t < 8) ? (featb + (size_t)an * F + t * 32)
                                   : (aggb + (size_t)an * F + (t - 8) * 32);
      a[rs] = *(const bf16x8*)(base + kq * 8);
    }
#pragma unroll
    for (int cs = 0; cs < 4; ++cs) {
      bf16x8 bb = *(const bf16x8*)(Wt + (((size_t)t * 4 + kq) * 256 + col0 + cs * 16 + r15) * 8);
#pragma unroll
      for (int rs = 0; rs < 4; ++rs)
        acc[rs][cs] = __builtin_amdgcn_mfma_f32_16x16x32_bf16(a[rs], bb, acc[rs][cs], 0, 0, 0);
    }
  }

  // C/D layout: col = lane&15, row = (lane>>4)*4 + reg   [m89-verified]
  const int rbase = kq * 4;
#pragma unroll
  for (int cs = 0; cs < 4; ++cs) {
    int col = col0 + cs * 16 + r15;
    float bv = bias[col];
#pragma unroll
    for (int rs = 0; rs < 4; ++rs) {
#pragma unroll
      for (int r = 0; r < 4; ++r) {
        int orow = m0 + rs * 16 + rbase + r;
        if (orow < N_NODES)
          out[(size_t)orow * F + col] = fmaxf(acc[rs][cs][r] + bv, 0.0f);
      }
    }
  }
}

extern "C" void kernel_launch(void* const* d_in, const int* in_sizes, int n_in,
                              void* d_out, int out_size, void* d_ws, size_t ws_size,
                              hipStream_t stream) {
  const float* feat = (const float*)d_in[0];
  const float* ew   = (const float*)d_in[1];
  const int*   src  = (const int*)d_in[2];
  const int*   dst  = (const int*)d_in[3];
  const float* Wm   = (const float*)d_in[4];
  const float* bias = (const float*)d_in[5];
  float* out = (float*)d_out;

  // workspace layout (8B-aligned first)
  u64*    bucket = (u64*)d_ws;                                  // N*SLOTS  (12.8 MB)
  __bf16* featb  = (__bf16*)(bucket + (size_t)N_NODES * SLOTS); // N*F      (5.12 MB)
  __bf16* aggb   = featb + (size_t)N_NODES * F;                 // N*F      (5.12 MB)
  __bf16* Wt     = aggb + (size_t)N_NODES * F;                  // F*K2     (0.26 MB)
  int*    cnt    = (int*)(Wt + (size_t)F * K2);                 // N

  prep_kernel<<<FEAT_BLOCKS + W_BLOCKS, 256, 0, stream>>>(feat, Wm, src, featb, Wt, cnt);
  scatter_kernel<<<(N_EDGES / 4 + 255) / 256, 256, 0, stream>>>(src, dst, ew, cnt, bucket);
  node_agg_kernel<<<(N_NODES * 64 + 255) / 256, 256, 0, stream>>>(featb, bucket, cnt, aggb);
  mfma_gemm_kernel<<<N_TILE64, 256, 0, stream>>>(featb, aggb, Wt, bias, out);
}

// Round 10
// 78.013 us; speedup vs baseline: 1.8976x; 1.1138x over previous
//
#include <hip/hip_runtime.h>

#define N_NODES 10000
#define N_EDGES 320000
#define F 256          // F_IN == F_OUT
#define K2 512         // 2*F_IN
#define SLOTS 160      // per-node bucket capacity (deg ~Poisson(32))
#define N_TILE16 625   // 10000/16 exactly
#define W_BLOCKS 128      // F*K2/4/256
#define CNT_BLOCKS 40     // 40*256 = 10240 >= N_NODES
#define CONV_BLOCKS 2500  // N*F/4/256
#define SCAT_BLOCKS 313   // ceil(80000/256)
#define LDSROW 264        // 256 + 8 bf16 pad -> 528B stride (2-way banks = free)

typedef __attribute__((ext_vector_type(8))) __bf16 bf16x8;
typedef __attribute__((ext_vector_type(4))) __bf16 bf16x4;
typedef __attribute__((ext_vector_type(4))) float f32x4;
typedef unsigned long long u64;
typedef unsigned int u32;
typedef unsigned short u16;

__device__ inline float bf2f(u16 u) { u32 x = ((u32)u) << 16; return __uint_as_float(x); }

// Wt layout: Wt[t][kq][col][8e], t=k/32, kq=(k%32)/8, e=k%8 (fragment-contiguous).

// ---------- dispatch 1: Wt (h0 folded) + cnt = 0
__global__ __launch_bounds__(256) void prep_kernel(
    const float* __restrict__ feat,
    const float* __restrict__ Wm,
    const int* __restrict__ src,
    __bf16* __restrict__ Wt,
    int* __restrict__ cnt) {
  int b = blockIdx.x;
  int tid = threadIdx.x;
  if (b < W_BLOCKS) {
    int idx = b * 256 + tid;                 // float4 index over W
    int o_ = idx >> 7;                       // 128 float4 per W row
    int k = (idx & 127) * 4;
    float4 w = ((const float4*)Wm)[idx];
    if (k >= F) {
      int s0 = src[0];
      float4 h = ((const float4*)(feat + (size_t)s0 * F))[(k - F) >> 2];
      w.x *= h.x; w.y *= h.y; w.z *= h.z; w.w *= h.w;
    }
    bf16x4 o;
    o[0] = (__bf16)w.x; o[1] = (__bf16)w.y; o[2] = (__bf16)w.z; o[3] = (__bf16)w.w;
    int t = k >> 5, kq = (k & 31) >> 3, e = k & 7;
    size_t offT = (((size_t)t * 4 + kq) * 256 + o_) * 8 + e;
    *(bf16x4*)(Wt + offT) = o;
  } else {
    int idx = (b - W_BLOCKS) * 256 + tid;
    if (idx < N_NODES) cnt[idx] = 0;
  }
}

// ---------- dispatch 2: feat->bf16 conversion (blocks 0..2499) || bucket scatter
__global__ __launch_bounds__(256) void conv_scatter_kernel(
    const float* __restrict__ feat,
    const int* __restrict__ src,
    const int* __restrict__ dst,
    const float* __restrict__ ew,
    __bf16* __restrict__ featb,
    int* __restrict__ cnt,
    u64* __restrict__ bucket) {
  int b = blockIdx.x;
  int tid = threadIdx.x;
  if (b < CONV_BLOCKS) {
    int idx = b * 256 + tid;                 // float4 index over feat
    float4 v = ((const float4*)feat)[idx];
    bf16x4 o;
    o[0] = (__bf16)v.x; o[1] = (__bf16)v.y; o[2] = (__bf16)v.z; o[3] = (__bf16)v.w;
    *(bf16x4*)(featb + (size_t)idx * 4) = o;
  } else {
    int i = (b - CONV_BLOCKS) * 256 + tid;
    if (i >= N_EDGES / 4) return;
    int4 s4 = ((const int4*)src)[i];
    int4 d4 = ((const int4*)dst)[i];
    float4 w4 = ((const float4*)ew)[i];
    int p;
    p = atomicAdd(&cnt[d4.x], 1);
    if (p < SLOTS) bucket[(size_t)d4.x * SLOTS + p] = ((u64)__float_as_uint(w4.x) << 32) | (u32)s4.x;
    p = atomicAdd(&cnt[d4.y], 1);
    if (p < SLOTS) bucket[(size_t)d4.y * SLOTS + p] = ((u64)__float_as_uint(w4.y) << 32) | (u32)s4.y;
    p = atomicAdd(&cnt[d4.z], 1);
    if (p < SLOTS) bucket[(size_t)d4.z * SLOTS + p] = ((u64)__float_as_uint(w4.z) << 32) | (u32)s4.z;
    p = atomicAdd(&cnt[d4.w], 1);
    if (p < SLOTS) bucket[(size_t)d4.w * SLOTS + p] = ((u64)__float_as_uint(w4.w) << 32) | (u32)s4.w;
  }
}

// ---------- dispatch 3: fused agg (LDS) + 16x256 MFMA tile, 625 blocks
__global__ __launch_bounds__(256) void fused_agg_gemm_kernel(
    const __bf16* __restrict__ featb,   // [N][F] plain
    const u64* __restrict__ bucket,     // [N][SLOTS]
    const int* __restrict__ cnt,        // [N]
    const __bf16* __restrict__ Wt,      // [16][4][256][8]
    const float* __restrict__ bias,
    float* __restrict__ out) {          // [N][F]
  __shared__ __bf16 aggs[16][LDSROW];   // 16 rows x 528B stride = 8.4KB

  const int tid = threadIdx.x;
  const int wave = tid >> 6;
  const int lane = tid & 63;
  const int m0 = blockIdx.x * 16;       // 625*16 == 10000 exactly

  // ---- agg phase: wave aggregates nodes m0 + wave*4 + j, j=0..3 (2500 waves grid-wide)
  const ushort4* f4 = (const ushort4*)featb;
  for (int j = 0; j < 4; ++j) {
    int node = m0 + wave * 4 + j;
    int c = cnt[node];
    int cc = min(c, SLOTS);
    const u64* bk = bucket + (size_t)node * SLOTS;
    float ax = 0.f, ay = 0.f, az = 0.f, aw = 0.f;
    int i = 0;
    for (; i + 8 <= cc; i += 8) {
      u64 p[8];
      ushort4 v[8];
#pragma unroll
      for (int q = 0; q < 8; ++q) p[q] = bk[i + q];
#pragma unroll
      for (int q = 0; q < 8; ++q) v[q] = f4[(size_t)(u32)p[q] * 64 + lane];
#pragma unroll
      for (int q = 0; q < 8; ++q) {
        float w = __uint_as_float((u32)(p[q] >> 32));
        ax += bf2f(v[q].x) * w; ay += bf2f(v[q].y) * w;
        az += bf2f(v[q].z) * w; aw += bf2f(v[q].w) * w;
      }
    }
    for (; i < cc; ++i) {
      u64 p0 = bk[i];
      ushort4 v0 = f4[(size_t)(u32)p0 * 64 + lane];
      float w0 = __uint_as_float((u32)(p0 >> 32));
      ax += bf2f(v0.x) * w0; ay += bf2f(v0.y) * w0;
      az += bf2f(v0.z) * w0; aw += bf2f(v0.w) * w0;
    }
    float ic = 1.0f / (float)max(c, 1);
    bf16x4 o;
    o[0] = (__bf16)(ax * ic); o[1] = (__bf16)(ay * ic);
    o[2] = (__bf16)(az * ic); o[3] = (__bf16)(aw * ic);
    *(bf16x4*)(&aggs[wave * 4 + j][lane * 4]) = o;
  }
  __syncthreads();

  // ---- gemm phase: 16 rows x 256 cols; wave = 16 rows x 64 cols
  const int r15 = lane & 15;
  const int kq = lane >> 4;
  const int col0 = wave * 64;

  f32x4 acc[4];
#pragma unroll
  for (int cs = 0; cs < 4; ++cs) acc[cs] = (f32x4){0.f, 0.f, 0.f, 0.f};

#pragma unroll
  for (int t = 0; t < 16; ++t) {
    bf16x8 a;
    if (t < 8) a = *(const bf16x8*)(featb + (size_t)(m0 + r15) * F + t * 32 + kq * 8);
    else       a = *(const bf16x8*)(&aggs[r15][(t - 8) * 32 + kq * 8]);
#pragma unroll
    for (int cs = 0; cs < 4; ++cs) {
      bf16x8 bb = *(const bf16x8*)(Wt + (((size_t)t * 4 + kq) * 256 + col0 + cs * 16 + r15) * 8);
      acc[cs] = __builtin_amdgcn_mfma_f32_16x16x32_bf16(a, bb, acc[cs], 0, 0, 0);
    }
  }

  // C/D layout: col = lane&15, row = (lane>>4)*4 + reg   [m89-verified]
  const int rbase = kq * 4;
#pragma unroll
  for (int cs = 0; cs < 4; ++cs) {
    int col = col0 + cs * 16 + r15;
    float bv = bias[col];
#pragma unroll
    for (int r = 0; r < 4; ++r) {
      int orow = m0 + rbase + r;
      out[(size_t)orow * F + col] = fmaxf(acc[cs][r] + bv, 0.0f);
    }
  }
}

extern "C" void kernel_launch(void* const* d_in, const int* in_sizes, int n_in,
                              void* d_out, int out_size, void* d_ws, size_t ws_size,
                              hipStream_t stream) {
  const float* feat = (const float*)d_in[0];
  const float* ew   = (const float*)d_in[1];
  const int*   src  = (const int*)d_in[2];
  const int*   dst  = (const int*)d_in[3];
  const float* Wm   = (const float*)d_in[4];
  const float* bias = (const float*)d_in[5];
  float* out = (float*)d_out;

  // workspace layout (8B-aligned first)
  u64*    bucket = (u64*)d_ws;                                  // N*SLOTS  (12.8 MB)
  __bf16* featb  = (__bf16*)(bucket + (size_t)N_NODES * SLOTS); // N*F      (5.12 MB)
  __bf16* Wt     = featb + (size_t)N_NODES * F;                 // F*K2     (0.26 MB)
  int*    cnt    = (int*)(Wt + (size_t)F * K2);                 // N

  prep_kernel<<<W_BLOCKS + CNT_BLOCKS, 256, 0, stream>>>(feat, Wm, src, Wt, cnt);
  conv_scatter_kernel<<<CONV_BLOCKS + SCAT_BLOCKS, 256, 0, stream>>>(
      feat, src, dst, ew, featb, cnt, bucket);
  fused_agg_gemm_kernel<<<N_TILE16, 256, 0, stream>>>(featb, bucket, cnt, Wt, bias, out);
}